// Round 17
// baseline (112.137 us; speedup 1.0000x reference)
//
#include <hip/hip_runtime.h>

// Bicubic (Catmull-Rom) warped interpolation.
// LDS-tiled, f16 VERTICAL-PAIR layout + fdot2 vertical combine.
// img/delta_x/delta_y: [B,C,H,W] fp32; out: fp32 clipped to [0,1]. H=W=1024.
// 64x64 tile / 256 threads. LDS dword (r, x) = f16 pair
// (img[gy0+r][x], img[gy0+r+1][x])  -- vertical pairs, overlapping storage.
// Pixel taps: for x-tap j in 0..3, ONE ds_read2_b32 at shared vaddr with
// offsets (j, 192+j) gives rows (y0-1,y0) and (y0+1,y0+2) -> 4 LDS instr /
// 8 dword-accesses per pixel (R13: 8/16). Vertical 4-tap via v_dot2_f32_f16
// with (wym1,wy0),(wy1,wy2) packed; horizontal via 4 scalar FMA.
// Banks: one dword per element-column -> bank = (lane + x-jitter) mod 32,
// stride-1 diagonal, y-jitter free (96 == 192 == 0 mod 32) -> ~2-3 lanes/bank.
// 28.8 KB LDS -> 5 blocks/CU. Weights packed f32 (R13 win); delta loads
// hoisted (R6 win). Rare fp32 global fallback (|delta| > ~6).

#define HD 1024
#define WD 1024
#define TILE 64
#define HALOX 8     // x halo; stage 80 cols (8 + 64 + 8)
#define HALOY 6     // y halo; stage img rows gy0..gy0+75
#define PROWS 75    // vertical-pair rows in LDS
#define SCOLS 80    // staged cols
#define DSTR 96     // dword stride per row (96 % 32 == 0 -> y-jitter bank-free)

typedef __attribute__((ext_vector_type(2))) _Float16 f16x2;   // fdot2 operand type
typedef __attribute__((ext_vector_type(2))) __fp16   h16x2;   // cvt_pkrtz return type
typedef __attribute__((ext_vector_type(2))) float    f32x2;

__device__ __forceinline__ float cubic_gather_global(
    const float* __restrict__ p, int x0, int y0,
    float wxm1, float wx0, float wx1, float wx2,
    float wym1, float wy0, float wy1, float wy2)
{
    int cx0 = min(max(x0 - 1, 0), WD - 1);
    int cx1 = min(max(x0,     0), WD - 1);
    int cx2 = min(max(x0 + 1, 0), WD - 1);
    int cx3 = min(max(x0 + 2, 0), WD - 1);
    int cy0 = min(max(y0 - 1, 0), HD - 1);
    int cy1 = min(max(y0,     0), HD - 1);
    int cy2 = min(max(y0 + 1, 0), HD - 1);
    int cy3 = min(max(y0 + 2, 0), HD - 1);
    const float* r0 = p + (size_t)cy0 * WD;
    const float* r1 = p + (size_t)cy1 * WD;
    const float* r2 = p + (size_t)cy2 * WD;
    const float* r3 = p + (size_t)cy3 * WD;
    float s0 = wxm1 * r0[cx0] + wx0 * r0[cx1] + wx1 * r0[cx2] + wx2 * r0[cx3];
    float s1 = wxm1 * r1[cx0] + wx0 * r1[cx1] + wx1 * r1[cx2] + wx2 * r1[cx3];
    float s2 = wxm1 * r2[cx0] + wx0 * r2[cx1] + wx1 * r2[cx2] + wx2 * r2[cx3];
    float s3 = wxm1 * r3[cx0] + wx0 * r3[cx1] + wx1 * r3[cx2] + wx2 * r3[cx3];
    return wym1 * s0 + wy0 * s1 + wy1 * s2 + wy2 * s3;
}

__device__ __forceinline__ uint32_t pk16(float a, float b) {
    h16x2 h = __builtin_amdgcn_cvt_pkrtz(a, b);
    return __builtin_bit_cast(uint32_t, h);
}
__device__ __forceinline__ f16x2 u2h(uint32_t u) {
    return __builtin_bit_cast(f16x2, u);
}

__global__ __launch_bounds__(256) void bicubic_tile_kernel(
    const float* __restrict__ img,
    const float* __restrict__ dxp,
    const float* __restrict__ dyp,
    float* __restrict__ out)
{
    __shared__ uint32_t smp[PROWS * DSTR];   // 28.8 KB -> 5 blocks/CU

    const int bx = blockIdx.x * TILE;
    const int by = blockIdx.y * TILE;
    const int plane = blockIdx.z;
    const float* __restrict__ p = img + (size_t)plane * (size_t)(HD * WD);

    const int gx0 = bx - HALOX;
    const int gy0 = by - HALOY;
    const int tid = threadIdx.x;

    // ---- stage 75 vertical-pair rows x 80 cols (edge-clamped) ----
    if (gx0 >= 0 && gx0 + SCOLS <= WD) {
        // interior: 20 quads/row; two float4 loads (rows r, r+1) -> 4 dwords
        for (int s = tid; s < PROWS * 20; s += 256) {
            int r = s / 20;
            int q = s - r * 20;
            int gya = min(max(gy0 + r,     0), HD - 1);
            int gyb = min(max(gy0 + r + 1, 0), HD - 1);
            const float* ra = p + (size_t)gya * WD + gx0;
            const float* rb = p + (size_t)gyb * WD + gx0;
            float4 a = *reinterpret_cast<const float4*>(ra + 4 * q);
            float4 b = *reinterpret_cast<const float4*>(rb + 4 * q);
            int o = r * DSTR + 4 * q;
            smp[o + 0] = pk16(a.x, b.x);
            smp[o + 1] = pk16(a.y, b.y);
            smp[o + 2] = pk16(a.z, b.z);
            smp[o + 3] = pk16(a.w, b.w);
        }
    } else {
        // edge tile: per-dword scalar staging with clamp
        for (int s = tid; s < PROWS * SCOLS; s += 256) {
            int r = s / SCOLS;
            int c = s - r * SCOLS;
            int gya = min(max(gy0 + r,     0), HD - 1);
            int gyb = min(max(gy0 + r + 1, 0), HD - 1);
            int e = min(max(gx0 + c, 0), WD - 1);
            smp[r * DSTR + c] = pk16(p[(size_t)gya * WD + e],
                                     p[(size_t)gyb * WD + e]);
        }
    }
    __syncthreads();

    // ---- compute: lane = column (64 consecutive cols/wave), 16 rows/thread
    const int col = bx + (tid & 63);
    const int rbase = by + (tid >> 6);
    const int didx0 = (plane << 20) | (rbase << 10) | col;

    // hoisted delta loads (R6 win: HBM latency hides under compute)
    float vdx[16], vdy[16];
    #pragma unroll
    for (int it = 0; it < 16; ++it) {
        vdx[it] = dxp[didx0 + it * 4096];
        vdy[it] = dyp[didx0 + it * 4096];
    }

    // x_map = ((x + dx - 512)/511 + 1)*511.5 == (x-512)*sc + 511.5 + dx*sc
    const float sc = 511.5f / 511.0f;
    const float colA = ((float)col - 512.0f) * sc + 511.5f;
    const float yA0 = ((float)rbase - 512.0f) * sc + 511.5f;
    const float yStep = 4.0f * sc;

    // packed polynomial constants
    const f32x2 cN05 = {-0.5f, -0.5f};
    const f32x2 cP05 = { 0.5f,  0.5f};
    const f32x2 cP1  = { 1.0f,  1.0f};
    const f32x2 cN1  = {-1.0f, -1.0f};
    const f32x2 cP2  = { 2.0f,  2.0f};
    const f32x2 cN25 = {-2.5f, -2.5f};
    const f32x2 cP15 = { 1.5f,  1.5f};
    const f32x2 cN15 = {-1.5f, -1.5f};

    #pragma unroll
    for (int it = 0; it < 16; ++it) {
        const int didx = didx0 + it * 4096;
        const float ddx = vdx[it];
        const float ddy = vdy[it];

        float x_map = fmaf(ddx, sc, colA);
        float y_map = fmaf(ddy, sc, yA0 + (float)it * yStep);

        float x0f = floorf(x_map);
        float y0f = floorf(y_map);
        int x0 = (int)x0f;
        int y0 = (int)y0f;

        // packed weights: .x = x-direction, .y = y-direction
        f32x2 t;
        t.x = x_map - x0f;
        t.y = y_map - y0f;
        f32x2 t2v = t * t;
        f32x2 t3v = t2v * t;
        f32x2 wm1 = __builtin_elementwise_fma(t3v, cN05,
                        __builtin_elementwise_fma(t, cN05, t2v));
        f32x2 w0v = __builtin_elementwise_fma(t3v, cP15,
                        __builtin_elementwise_fma(t2v, cN25, cP1));
        f32x2 w1v = __builtin_elementwise_fma(t3v, cN15,
                        __builtin_elementwise_fma(t2v, cP2, t * cP05));
        f32x2 w2v = __builtin_elementwise_fma(wm1 + w0v + w1v, cN1, cP1);

        const int lx = x0 - 1 - gx0;   // 0..76 valid (covers jx in [-7, 6])
        const int ly = y0 - 1 - gy0;   // pair rows ly, ly+2; need ly+2 <= 74
        const bool inb = ((unsigned)lx <= (unsigned)(SCOLS - 4)) &
                         ((unsigned)ly <= (unsigned)(PROWS - 3));

        float acc;
        if (inb) {
            // y-weights to f16 pairs: (wym1, wy0) and (wy1, wy2)
            f16x2 wya = u2h(pk16(wm1.y, w0v.y));
            f16x2 wyb = u2h(pk16(w1v.y, w2v.y));
            const int base = ly * DSTR + lx;
            // 4 x-taps: one ds_read2_b32 each, shared vaddr, offsets (j, 192+j)
            uint32_t u0 = smp[base + 0], v0 = smp[base + 2 * DSTR + 0];
            uint32_t u1 = smp[base + 1], v1 = smp[base + 2 * DSTR + 1];
            uint32_t u2 = smp[base + 2], v2 = smp[base + 2 * DSTR + 2];
            uint32_t u3 = smp[base + 3], v3 = smp[base + 2 * DSTR + 3];
            // vertical combine per x-tap (f32 accumulate)
            float c0 = __builtin_amdgcn_fdot2(wya, u2h(u0),
                         __builtin_amdgcn_fdot2(wyb, u2h(v0), 0.0f, false), false);
            float c1 = __builtin_amdgcn_fdot2(wya, u2h(u1),
                         __builtin_amdgcn_fdot2(wyb, u2h(v1), 0.0f, false), false);
            float c2 = __builtin_amdgcn_fdot2(wya, u2h(u2),
                         __builtin_amdgcn_fdot2(wyb, u2h(v2), 0.0f, false), false);
            float c3 = __builtin_amdgcn_fdot2(wya, u2h(u3),
                         __builtin_amdgcn_fdot2(wyb, u2h(v3), 0.0f, false), false);
            // horizontal combine (scalar f32)
            acc = wm1.x * c0 + w0v.x * c1 + w1v.x * c2 + w2v.x * c3;
        } else {
            acc = cubic_gather_global(p, x0, y0, wm1.x, w0v.x, w1v.x, w2v.x,
                                      wm1.y, w0v.y, w1v.y, w2v.y);
        }
        out[didx] = fminf(fmaxf(acc, 0.0f), 1.0f);
    }
}

extern "C" void kernel_launch(void* const* d_in, const int* in_sizes, int n_in,
                              void* d_out, int out_size, void* d_ws, size_t ws_size,
                              hipStream_t stream) {
    const float* img = (const float*)d_in[0];
    const float* dxp = (const float*)d_in[1];
    const float* dyp = (const float*)d_in[2];
    float* out = (float*)d_out;

    const int planes = in_sizes[0] / (HD * WD);  // B*C = 24
    dim3 grid(WD / TILE, HD / TILE, planes);
    bicubic_tile_kernel<<<grid, 256, 0, stream>>>(img, dxp, dyp, out);
}

// Round 20
// 90.890 us; speedup vs baseline: 1.2338x; 1.2338x over previous
//
#include <hip/hip_runtime.h>

// Bicubic (Catmull-Rom) warped interpolation, LDS-tiled (R13 substrate) +
// explicit 2-deep software pipeline with named register sets (inline fns).
// img/delta_x/delta_y: [B,C,H,W] fp32; out: fp32 clipped to [0,1]. H=W=1024.
// 64x64 tile / 256 threads; 80x80 fp32 patch, stride 96 (bank = lane +
// x-jitter only). Per px: 8 ds_read2_b32 (row pairs at same x) + packed-f32
// weight math (R13 wins). NEW: iteration it+1's address calc + 8 LDS reads
// (two named register sets A/B held in structs passed by reference to
// forceinline stage functions) issue BEFORE iteration it's math -> ~120cy
// LDS latency hides under ~40 VALU ops. Reads use clamped addresses; rare
// out-of-patch results overwritten by the fp32 global fallback in the math
// stage. Delta loads hoisted (R6 win).

#define HD 1024
#define WD 1024
#define TILE 64
#define HALO 8
#define SROWS 80   // staged rows & cols of valid data
#define SSTR 96    // LDS row stride in floats; 96 % 32 == 0 -> bank = lx % 32

typedef __attribute__((ext_vector_type(2))) float f32x2;

__device__ __forceinline__ float cubic_gather_global(
    const float* __restrict__ p, int x0, int y0,
    float wxm1, float wx0, float wx1, float wx2,
    float wym1, float wy0, float wy1, float wy2)
{
    int cx0 = min(max(x0 - 1, 0), WD - 1);
    int cx1 = min(max(x0,     0), WD - 1);
    int cx2 = min(max(x0 + 1, 0), WD - 1);
    int cx3 = min(max(x0 + 2, 0), WD - 1);
    int cy0 = min(max(y0 - 1, 0), HD - 1);
    int cy1 = min(max(y0,     0), HD - 1);
    int cy2 = min(max(y0 + 1, 0), HD - 1);
    int cy3 = min(max(y0 + 2, 0), HD - 1);
    const float* r0 = p + (size_t)cy0 * WD;
    const float* r1 = p + (size_t)cy1 * WD;
    const float* r2 = p + (size_t)cy2 * WD;
    const float* r3 = p + (size_t)cy3 * WD;
    float s0 = wxm1 * r0[cx0] + wx0 * r0[cx1] + wx1 * r0[cx2] + wx2 * r0[cx3];
    float s1 = wxm1 * r1[cx0] + wx0 * r1[cx1] + wx1 * r1[cx2] + wx2 * r1[cx3];
    float s2 = wxm1 * r2[cx0] + wx0 * r2[cx1] + wx1 * r2[cx2] + wx2 * r2[cx3];
    float s3 = wxm1 * r3[cx0] + wx0 * r3[cx1] + wx1 * r3[cx2] + wx2 * r3[cx3];
    return wym1 * s0 + wy0 * s1 + wy1 * s2 + wy2 * s3;
}

// pipeline state: one iteration's taps + coords (kept in VGPRs when inlined)
struct PipeState {
    f32x2 t;
    int x0, y0, inb;
    f32x2 q0, q1, q2, q3, r0, r1, r2, r3;
};

// L: address math + issue 8 paired LDS reads (clamped -> always safe)
__device__ __forceinline__ void L_stage(
    PipeState& S, const float* sm, float ddx, float ddy,
    float colA, float yA, float sc, int gx0, int gy0)
{
    float x_map = fmaf(ddx, sc, colA);
    float y_map = fmaf(ddy, sc, yA);
    float x0f = floorf(x_map);
    float y0f = floorf(y_map);
    S.t.x = x_map - x0f;
    S.t.y = y_map - y0f;
    int x0i = (int)x0f, y0i = (int)y0f;
    S.x0 = x0i; S.y0 = y0i;
    int lx = x0i - 1 - gx0, ly = y0i - 1 - gy0;
    S.inb = (lx >= 0) & (lx <= SROWS - 4) & (ly >= 0) & (ly <= SROWS - 4);
    int lxc = min(max(lx, 0), SROWS - 4);
    int lyc = min(max(ly, 0), SROWS - 4);
    const float* bb  = &sm[lyc * SSTR + lxc];
    const float* bb2 = bb + 2 * SSTR;
    S.q0.x = bb[0];  S.q0.y = bb[SSTR + 0];
    S.q1.x = bb[1];  S.q1.y = bb[SSTR + 1];
    S.q2.x = bb[2];  S.q2.y = bb[SSTR + 2];
    S.q3.x = bb[3];  S.q3.y = bb[SSTR + 3];
    S.r0.x = bb2[0]; S.r0.y = bb2[SSTR + 0];
    S.r1.x = bb2[1]; S.r1.y = bb2[SSTR + 1];
    S.r2.x = bb2[2]; S.r2.y = bb2[SSTR + 2];
    S.r3.x = bb2[3]; S.r3.y = bb2[SSTR + 3];
}

// M: packed weights + combine + rare fallback + store
__device__ __forceinline__ void M_stage(
    const PipeState& S, const float* __restrict__ p, float* __restrict__ out,
    int didx)
{
    const f32x2 cN05 = {-0.5f, -0.5f};
    const f32x2 cP05 = { 0.5f,  0.5f};
    const f32x2 cP1  = { 1.0f,  1.0f};
    const f32x2 cN1  = {-1.0f, -1.0f};
    const f32x2 cP2  = { 2.0f,  2.0f};
    const f32x2 cN25 = {-2.5f, -2.5f};
    const f32x2 cP15 = { 1.5f,  1.5f};
    const f32x2 cN15 = {-1.5f, -1.5f};

    f32x2 t2v = S.t * S.t;
    f32x2 t3v = t2v * S.t;
    f32x2 wm1 = __builtin_elementwise_fma(t3v, cN05,
                    __builtin_elementwise_fma(S.t, cN05, t2v));
    f32x2 w0v = __builtin_elementwise_fma(t3v, cP15,
                    __builtin_elementwise_fma(t2v, cN25, cP1));
    f32x2 w1v = __builtin_elementwise_fma(t3v, cN15,
                    __builtin_elementwise_fma(t2v, cP2, S.t * cP05));
    f32x2 w2v = __builtin_elementwise_fma(wm1 + w0v + w1v, cN1, cP1);

    f32x2 s01 = __builtin_elementwise_fma(w2v.xx, S.q3,
                    __builtin_elementwise_fma(w1v.xx, S.q2,
                        __builtin_elementwise_fma(w0v.xx, S.q1,
                            wm1.xx * S.q0)));
    f32x2 s23 = __builtin_elementwise_fma(w2v.xx, S.r3,
                    __builtin_elementwise_fma(w1v.xx, S.r2,
                        __builtin_elementwise_fma(w0v.xx, S.r1,
                            wm1.xx * S.r0)));
    float acc = wm1.y * s01.x + w0v.y * s01.y + w1v.y * s23.x + w2v.y * s23.y;
    if (!S.inb)
        acc = cubic_gather_global(p, S.x0, S.y0,
                                  wm1.x, w0v.x, w1v.x, w2v.x,
                                  wm1.y, w0v.y, w1v.y, w2v.y);
    out[didx] = fminf(fmaxf(acc, 0.0f), 1.0f);
}

__global__ __launch_bounds__(256) void bicubic_tile_kernel(
    const float* __restrict__ img,
    const float* __restrict__ dxp,
    const float* __restrict__ dyp,
    float* __restrict__ out)
{
    __shared__ float sm[SROWS * SSTR];   // 30.7 KB -> 5 blocks/CU

    const int bx = blockIdx.x * TILE;
    const int by = blockIdx.y * TILE;
    const int plane = blockIdx.z;
    const float* __restrict__ p = img + (size_t)plane * (size_t)(HD * WD);

    const int gx0 = bx - HALO;
    const int gy0 = by - HALO;
    const int tid = threadIdx.x;

    // ---- stage 80x80 patch at (gy0, gx0) into LDS (edge-clamped) ----
    if (gx0 >= 0 && gx0 + SROWS <= WD) {
        for (int s = tid; s < SROWS * (SROWS / 4); s += 256) {
            int r = s / (SROWS / 4);
            int q = s - r * (SROWS / 4);
            int gy = min(max(gy0 + r, 0), HD - 1);
            float4 v = *reinterpret_cast<const float4*>(p + (size_t)gy * WD + gx0 + 4 * q);
            int b = r * SSTR + 4 * q;
            sm[b + 0] = v.x; sm[b + 1] = v.y; sm[b + 2] = v.z; sm[b + 3] = v.w;
        }
    } else {
        for (int s = tid; s < SROWS * SROWS; s += 256) {
            int r = s / SROWS;
            int c = s - r * SROWS;
            int gy = min(max(gy0 + r, 0), HD - 1);
            int gx = min(max(gx0 + c, 0), WD - 1);
            sm[r * SSTR + c] = p[(size_t)gy * WD + gx];
        }
    }
    __syncthreads();

    // ---- compute: lane = column (64 consecutive cols/wave), 16 rows/thread
    const int col = bx + (tid & 63);
    const int rbase = by + (tid >> 6);
    const int didx0 = (plane << 20) | (rbase << 10) | col;

    // hoisted delta loads (R6 win)
    float vdx[16], vdy[16];
    #pragma unroll
    for (int it = 0; it < 16; ++it) {
        vdx[it] = dxp[didx0 + it * 4096];
        vdy[it] = dyp[didx0 + it * 4096];
    }

    const float sc = 511.5f / 511.0f;
    const float colA = ((float)col - 512.0f) * sc + 511.5f;
    const float yA0 = ((float)rbase - 512.0f) * sc + 511.5f;
    const float yStep = 4.0f * sc;

    PipeState SA, SB;

    L_stage(SA, sm, vdx[0], vdy[0], colA, yA0, sc, gx0, gy0);
    #pragma unroll
    for (int it = 0; it < 16; ++it) {
        const float yA_next = yA0 + (float)(it + 1) * yStep;
        if ((it & 1) == 0) {
            if (it < 15) L_stage(SB, sm, vdx[it + 1], vdy[it + 1], colA, yA_next, sc, gx0, gy0);
            M_stage(SA, p, out, didx0 + it * 4096);
        } else {
            if (it < 15) L_stage(SA, sm, vdx[it + 1], vdy[it + 1], colA, yA_next, sc, gx0, gy0);
            M_stage(SB, p, out, didx0 + it * 4096);
        }
    }
}

extern "C" void kernel_launch(void* const* d_in, const int* in_sizes, int n_in,
                              void* d_out, int out_size, void* d_ws, size_t ws_size,
                              hipStream_t stream) {
    const float* img = (const float*)d_in[0];
    const float* dxp = (const float*)d_in[1];
    const float* dyp = (const float*)d_in[2];
    float* out = (float*)d_out;

    const int planes = in_sizes[0] / (HD * WD);  // B*C = 24
    dim3 grid(WD / TILE, HD / TILE, planes);
    bicubic_tile_kernel<<<grid, 256, 0, stream>>>(img, dxp, dyp, out);
}

// Round 21
// 89.380 us; speedup vs baseline: 1.2546x; 1.0169x over previous
//
#include <hip/hip_runtime.h>

// Bicubic (Catmull-Rom) warped interpolation — FINAL (best config, R13).
// LDS-tiled (80x80 fp32 patch, stride 96) + packed-fp32 math (v_pk_fma_f32)
// + paired LDS reads (ds_read2_b32) + hoisted delta prefetch.
// img/delta_x/delta_y: [B,C,H,W] fp32; out: fp32 clipped to [0,1]. H=W=1024.
//
// Optimization history (what worked / what was falsified):
//  - LDS tiling of the gather (R1):      342 -> 138 us
//  - lane = column mapping (R2):         conflicts 3.1e7 -> 2.4e7
//  - delta-load register prefetch (R6):  118 -> 94.7 us (latency hiding; WIN)
//  - stride 96 == 0 mod 32 (R11):        bank = lane + x-jitter only (small win)
//  - packed f32 weights + ds_read2 (R13): 92.9 -> 89.4 us (WIN)
//  FALSIFIED by controlled experiments: bank conflicts on critical path
//  (-50% conflicts twice -> <=2us), LDS instruction count (f16 dual-phase,
//  alignbit, vertical-pair all regressed via conversion/occupancy costs),
//  occupancy (+15pts twice -> regression), software pipelining (compiler
//  collapses source-level schedules; 3 attempts neutral).
//  Structural floor: 201M data-dependent ds_read2 ops across 256 CUs.

#define HD 1024
#define WD 1024
#define TILE 64
#define HALO 8
#define SROWS 80   // staged rows & cols of valid data
#define SSTR 96    // LDS row stride in floats; 96 % 32 == 0 -> bank = lx % 32

typedef __attribute__((ext_vector_type(2))) float f32x2;

__device__ __forceinline__ float cubic_gather_global(
    const float* __restrict__ p, int x0, int y0,
    float wxm1, float wx0, float wx1, float wx2,
    float wym1, float wy0, float wy1, float wy2)
{
    int cx0 = min(max(x0 - 1, 0), WD - 1);
    int cx1 = min(max(x0,     0), WD - 1);
    int cx2 = min(max(x0 + 1, 0), WD - 1);
    int cx3 = min(max(x0 + 2, 0), WD - 1);
    int cy0 = min(max(y0 - 1, 0), HD - 1);
    int cy1 = min(max(y0,     0), HD - 1);
    int cy2 = min(max(y0 + 1, 0), HD - 1);
    int cy3 = min(max(y0 + 2, 0), HD - 1);
    const float* r0 = p + (size_t)cy0 * WD;
    const float* r1 = p + (size_t)cy1 * WD;
    const float* r2 = p + (size_t)cy2 * WD;
    const float* r3 = p + (size_t)cy3 * WD;
    float s0 = wxm1 * r0[cx0] + wx0 * r0[cx1] + wx1 * r0[cx2] + wx2 * r0[cx3];
    float s1 = wxm1 * r1[cx0] + wx0 * r1[cx1] + wx1 * r1[cx2] + wx2 * r1[cx3];
    float s2 = wxm1 * r2[cx0] + wx0 * r2[cx1] + wx1 * r2[cx2] + wx2 * r2[cx3];
    float s3 = wxm1 * r3[cx0] + wx0 * r3[cx1] + wx1 * r3[cx2] + wx2 * r3[cx3];
    return wym1 * s0 + wy0 * s1 + wy1 * s2 + wy2 * s3;
}

__global__ __launch_bounds__(256) void bicubic_tile_kernel(
    const float* __restrict__ img,
    const float* __restrict__ dxp,
    const float* __restrict__ dyp,
    float* __restrict__ out)
{
    __shared__ float sm[SROWS * SSTR];   // 30.7 KB

    const int bx = blockIdx.x * TILE;
    const int by = blockIdx.y * TILE;
    const int plane = blockIdx.z;
    const float* __restrict__ p = img + (size_t)plane * (size_t)(HD * WD);

    const int gx0 = bx - HALO;
    const int gy0 = by - HALO;
    const int tid = threadIdx.x;

    // ---- stage 80x80 patch at (gy0, gx0) into LDS (edge-clamped) ----
    if (gx0 >= 0 && gx0 + SROWS <= WD) {
        for (int s = tid; s < SROWS * (SROWS / 4); s += 256) {
            int r = s / (SROWS / 4);
            int q = s - r * (SROWS / 4);
            int gy = min(max(gy0 + r, 0), HD - 1);
            float4 v = *reinterpret_cast<const float4*>(p + (size_t)gy * WD + gx0 + 4 * q);
            int b = r * SSTR + 4 * q;
            sm[b + 0] = v.x; sm[b + 1] = v.y; sm[b + 2] = v.z; sm[b + 3] = v.w;
        }
    } else {
        for (int s = tid; s < SROWS * SROWS; s += 256) {
            int r = s / SROWS;
            int c = s - r * SROWS;
            int gy = min(max(gy0 + r, 0), HD - 1);
            int gx = min(max(gx0 + c, 0), WD - 1);
            sm[r * SSTR + c] = p[(size_t)gy * WD + gx];
        }
    }
    __syncthreads();

    // ---- compute: lane = column (64 consecutive cols/wave), 16 rows/thread
    const int col = bx + (tid & 63);
    const int rbase = by + (tid >> 6);
    const int didx0 = (plane << 20) | (rbase << 10) | col;

    // hoisted delta loads (R6 win: HBM latency hides under compute)
    float vdx[16], vdy[16];
    #pragma unroll
    for (int it = 0; it < 16; ++it) {
        vdx[it] = dxp[didx0 + it * 4096];
        vdy[it] = dyp[didx0 + it * 4096];
    }

    // x_map = ((x + dx - 512)/511 + 1)*511.5 == (x-512)*sc + 511.5 + dx*sc
    const float sc = 511.5f / 511.0f;
    const float colA = ((float)col - 512.0f) * sc + 511.5f;
    const float yA0 = ((float)rbase - 512.0f) * sc + 511.5f;
    const float yStep = 4.0f * sc;

    // packed polynomial constants
    const f32x2 cN05 = {-0.5f, -0.5f};
    const f32x2 cP05 = { 0.5f,  0.5f};
    const f32x2 cP1  = { 1.0f,  1.0f};
    const f32x2 cN1  = {-1.0f, -1.0f};
    const f32x2 cP2  = { 2.0f,  2.0f};
    const f32x2 cN25 = {-2.5f, -2.5f};
    const f32x2 cP15 = { 1.5f,  1.5f};
    const f32x2 cN15 = {-1.5f, -1.5f};

    #pragma unroll
    for (int it = 0; it < 16; ++it) {
        const int didx = didx0 + it * 4096;
        const float ddx = vdx[it];
        const float ddy = vdy[it];

        float x_map = fmaf(ddx, sc, colA);
        float y_map = fmaf(ddy, sc, yA0 + (float)it * yStep);

        float x0f = floorf(x_map);
        float y0f = floorf(y_map);
        int x0 = (int)x0f;
        int y0 = (int)y0f;

        // packed weights: lane .x = x-direction, lane .y = y-direction
        f32x2 t;
        t.x = x_map - x0f;
        t.y = y_map - y0f;
        f32x2 t2v = t * t;
        f32x2 t3v = t2v * t;
        // wm1 = -0.5 t3 + t2 - 0.5 t
        f32x2 wm1 = __builtin_elementwise_fma(t3v, cN05,
                        __builtin_elementwise_fma(t, cN05, t2v));
        // w0 = 1.5 t3 - 2.5 t2 + 1
        f32x2 w0v = __builtin_elementwise_fma(t3v, cP15,
                        __builtin_elementwise_fma(t2v, cN25, cP1));
        // w1 = -1.5 t3 + 2 t2 + 0.5 t
        f32x2 w1v = __builtin_elementwise_fma(t3v, cN15,
                        __builtin_elementwise_fma(t2v, cP2, t * cP05));
        // w2 = 1 - (wm1 + w0 + w1)
        f32x2 w2v = __builtin_elementwise_fma(wm1 + w0v + w1v, cN1, cP1);

        const int lx = x0 - 1 - gx0;
        const int ly = y0 - 1 - gy0;
        const bool inb = (lx >= 0) & (lx <= SROWS - 4) & (ly >= 0) & (ly <= SROWS - 4);

        float acc;
        if (inb) {
            const float* b  = &sm[ly * SSTR + lx];
            const float* b2 = b + 2 * SSTR;
            // row-pairs at same x -> ds_read2_b32 (offset0:j offset1:96+j)
            f32x2 q0, q1, q2, q3, r0, r1, r2, r3;
            q0.x = b[0];  q0.y = b[SSTR + 0];
            q1.x = b[1];  q1.y = b[SSTR + 1];
            q2.x = b[2];  q2.y = b[SSTR + 2];
            q3.x = b[3];  q3.y = b[SSTR + 3];
            r0.x = b2[0]; r0.y = b2[SSTR + 0];
            r1.x = b2[1]; r1.y = b2[SSTR + 1];
            r2.x = b2[2]; r2.y = b2[SSTR + 2];
            r3.x = b2[3]; r3.y = b2[SSTR + 3];
            // packed horizontal combine: s01 = (s_row0, s_row1), s23 = (s_row2, s_row3)
            f32x2 s01 = __builtin_elementwise_fma(w2v.xx, q3,
                            __builtin_elementwise_fma(w1v.xx, q2,
                                __builtin_elementwise_fma(w0v.xx, q1, wm1.xx * q0)));
            f32x2 s23 = __builtin_elementwise_fma(w2v.xx, r3,
                            __builtin_elementwise_fma(w1v.xx, r2,
                                __builtin_elementwise_fma(w0v.xx, r1, wm1.xx * r0)));
            // vertical combine (scalar, 4 ops)
            acc = wm1.y * s01.x + w0v.y * s01.y + w1v.y * s23.x + w2v.y * s23.y;
        } else {
            acc = cubic_gather_global(p, x0, y0, wm1.x, w0v.x, w1v.x, w2v.x,
                                      wm1.y, w0v.y, w1v.y, w2v.y);
        }
        out[didx] = fminf(fmaxf(acc, 0.0f), 1.0f);
    }
}

extern "C" void kernel_launch(void* const* d_in, const int* in_sizes, int n_in,
                              void* d_out, int out_size, void* d_ws, size_t ws_size,
                              hipStream_t stream) {
    const float* img = (const float*)d_in[0];
    const float* dxp = (const float*)d_in[1];
    const float* dyp = (const float*)d_in[2];
    float* out = (float*)d_out;

    const int planes = in_sizes[0] / (HD * WD);  // B*C = 24
    dim3 grid(WD / TILE, HD / TILE, planes);
    bicubic_tile_kernel<<<grid, 256, 0, stream>>>(img, dxp, dyp, out);
}